// Round 1
// baseline (429.148 us; speedup 1.0000x reference)
//
#include <hip/hip_runtime.h>

typedef _Float16 h8 __attribute__((ext_vector_type(8)));
typedef float f4 __attribute__((ext_vector_type(4)));

#define MFMA16(a, b, c) __builtin_amdgcn_mfma_f32_16x16x32_f16((a), (b), (c), 0, 0, 0)

__device__ static inline void gl_lds16(const void* g, void* l) {
  __builtin_amdgcn_global_load_lds((const __attribute__((address_space(1))) unsigned int*)g,
                                   (__attribute__((address_space(3))) unsigned int*)l, 16, 0, 0);
}

// B=4, S=4096, D=512.
// IMG block = 16KB = 128 rows x 64 k fp16; half-offset(r,k) = r*64 + ((((k>>3)&7)^(r&7))<<3) + (k&7).
// XOR-8 swizzle baked in global so linear global_load_lds staging yields bank-floor ds_read_b128 frags.
//  Qimg/Kimg: block(b, rb=s>>7, kc=d>>6) at ((b*32+rb)*8+kc)*16KB        [16MB each]
//  VTimg:     block(b, rb=d>>7, kc=s>>6) at ((b*4+rb)*64+kc)*16KB        [16MB]
//  Wt:        block(z, rb=n>>7, kc=k>>6) at ((z*4+rb)*8+kc)*16KB         [1.5MB]
//  Simg(chunk): block(rbL, kc=t>>6) at (rbL*64+kc)*16KB, rbL = chunk-row>>7

// ---------------- weight convert ----------------
__global__ void wconv_kernel(const float* __restrict__ Wq, const float* __restrict__ Wk,
                             const float* __restrict__ Wv, _Float16* __restrict__ Wt) {
  int idx = blockIdx.x * 256 + threadIdx.x;
  int z = idx >> 15, rem = idx & 32767;
  int n = rem >> 6, k0 = (rem & 63) << 3;
  const float* W = (z == 0) ? Wq : (z == 1) ? Wk : Wv;
  float sc = (z == 0) ? 0.5f : 1.0f;
  h8 v;
#pragma unroll
  for (int j = 0; j < 8; ++j) v[j] = (_Float16)(W[(k0 + j) * 512 + n] * sc);
  size_t blk = (size_t)((z * 4 + (n >> 7)) * 8 + (k0 >> 6));
  int off = (n & 127) * 64 + ((((k0 >> 3) & 7) ^ (n & 7)) << 3);
  *(h8*)&Wt[blk * 8192 + off] = v;
}

// ---------------- QKV projection -> images ----------------
__global__ __launch_bounds__(256, 3)
void proj_kernel(const float* __restrict__ x, const _Float16* __restrict__ Wt,
                 const float* __restrict__ bq, const float* __restrict__ bk,
                 const float* __restrict__ bv,
                 char* __restrict__ Qimg, char* __restrict__ Kimg, char* __restrict__ VTimg) {
  __shared__ _Float16 sMem[16384];  // sA 8192 + sB 8192; epilogue stash 16384
  _Float16* sA = sMem;
  _Float16* sB = sMem + 8192;
  const int tid = threadIdx.x;
  const int wave = tid >> 6, lane = tid & 63;
  const int quad = lane >> 4, lr = lane & 15;
  const int mbase = blockIdx.x * 128, nbase = blockIdx.y * 128, z = blockIdx.z;
  const int sr = tid >> 1, sseg = tid & 1;
  const int rbase = (wave & 1) * 64, cbase = (wave >> 1) * 64;
  const char* WtB = (const char*)Wt + ((size_t)(z * 4 + (nbase >> 7)) * 8) * 16384;

  float4 ax[8];
  f4 acc[4][4];
#pragma unroll
  for (int i = 0; i < 4; ++i)
#pragma unroll
    for (int j = 0; j < 4; ++j) { f4 zz = {0.f, 0.f, 0.f, 0.f}; acc[i][j] = zz; }

  {  // preload ax(0), stage B(0)
    const float4* asrc = (const float4*)&x[(size_t)(mbase + sr) * 512 + sseg * 32];
#pragma unroll
    for (int i = 0; i < 8; ++i) ax[i] = asrc[i];
#pragma unroll
    for (int j = 0; j < 4; ++j)
      gl_lds16(WtB + tid * 16 + j * 4096, (char*)sB + tid * 16 + j * 4096);
  }

  for (int kt = 0; kt < 8; ++kt) {
    if (kt > 0) __syncthreads();  // FREE: readers of kt-1 done
    // sA(kt) from ax (fp32->fp16, swizzled)
#pragma unroll
    for (int i = 0; i < 4; ++i) {
      h8 v;
      float4 f0 = ax[2 * i], f1 = ax[2 * i + 1];
      v[0] = (_Float16)f0.x; v[1] = (_Float16)f0.y; v[2] = (_Float16)f0.z; v[3] = (_Float16)f0.w;
      v[4] = (_Float16)f1.x; v[5] = (_Float16)f1.y; v[6] = (_Float16)f1.z; v[7] = (_Float16)f1.w;
      *(h8*)&sA[sr * 64 + (((sseg * 4 + i) ^ (sr & 7)) << 3)] = v;
    }
    if (kt > 0) {  // stage B(kt)
#pragma unroll
      for (int j = 0; j < 4; ++j)
        gl_lds16(WtB + kt * 16384 + tid * 16 + j * 4096, (char*)sB + tid * 16 + j * 4096);
    }
    __syncthreads();  // DRAIN
    if (kt < 7) {
      const float4* asrc = (const float4*)&x[(size_t)(mbase + sr) * 512 + (kt + 1) * 64 + sseg * 32];
#pragma unroll
      for (int i = 0; i < 8; ++i) ax[i] = asrc[i];
    }
#pragma unroll
    for (int ks = 0; ks < 2; ++ks) {
      h8 a[4], bb[4];
#pragma unroll
      for (int rt = 0; rt < 4; ++rt) {
        const int r = rbase + rt * 16 + lr;
        a[rt] = *(const h8*)&sA[r * 64 + ((((ks << 2) | quad) ^ (lr & 7)) << 3)];
      }
#pragma unroll
      for (int ct = 0; ct < 4; ++ct) {
        const int r = cbase + ct * 16 + lr;
        bb[ct] = *(const h8*)&sB[r * 64 + ((((ks << 2) | quad) ^ (lr & 7)) << 3)];
      }
#pragma unroll
      for (int rt = 0; rt < 4; ++rt)
#pragma unroll
        for (int ct = 0; ct < 4; ++ct)
          acc[rt][ct] = MFMA16(a[rt], bb[ct], acc[rt][ct]);
    }
  }

  // ---- epilogue: swizzled stash -> coalesced image stores ----
  const float* bias = (z == 0) ? bq : (z == 1) ? bk : bv;
  const float bscale = (z == 0) ? 0.5f : 1.0f;
  _Float16* sC = sMem;
  __syncthreads();
#pragma unroll
  for (int ct = 0; ct < 4; ++ct) {
    const int dl = cbase + ct * 16 + lr;
    const float bb = bias[nbase + dl] * bscale;
#pragma unroll
    for (int rt = 0; rt < 4; ++rt) {
#pragma unroll
      for (int r = 0; r < 4; ++r) {
        const int sl = rbase + rt * 16 + quad * 4 + r;
        const _Float16 val = (_Float16)(acc[rt][ct][r] + bb);
        if (z == 2) {  // VT: row=d, k=s
          sC[((sl >> 6) << 13) + dl * 64 + ((((sl >> 3) & 7) ^ (dl & 7)) << 3) + (sl & 7)] = val;
        } else {       // Q/K: row=s, k=d
          sC[((dl >> 6) << 13) + sl * 64 + ((((dl >> 3) & 7) ^ (sl & 7)) << 3) + (dl & 7)] = val;
        }
      }
    }
  }
  __syncthreads();
  const int b_ = mbase >> 12;
  char* dst;
  if (z != 2) {
    char* img = (z == 0) ? Qimg : Kimg;
    dst = img + ((size_t)((b_ * 32 + ((mbase & 4095) >> 7)) * 8 + (nbase >> 6) + (tid >> 7))) * 16384;
  } else {
    dst = VTimg + ((size_t)((b_ * 4 + (nbase >> 7)) * 64 + ((mbase & 4095) >> 6) + (tid >> 7))) * 16384;
  }
  dst += (size_t)(tid & 127) * 128;
#pragma unroll
  for (int k = 0; k < 8; ++k)
    *(int4*)(dst + k * 16) = *(const int4*)&sC[tid * 64 + k * 8];
}

// ---------------- QK GEMM, 8-phase 256x256 schedule ----------------
// 8 waves (2x4), per-wave C = 128x64. LDS = ring of 8 half-tile slots (16KB each):
// slot(parity p, {0:B0,1:B1,2:A0,3:A1}). Per K-tile (BK=64), 4 phases; each phase
// stages exactly 1 half-tile; stage ptr runs 3 HTs ahead -> boundary wait vmcnt(6).
#define STAGE(src, slot)                                                        \
  gl_lds16((src) + tid * 16, (char*)sMem + (slot) * 16384 + tid * 16);          \
  gl_lds16((src) + tid * 16 + 8192, (char*)sMem + (slot) * 16384 + tid * 16 + 8192)

__global__ __launch_bounds__(512, 2)
void qk_kernel(const char* __restrict__ Qimg, const char* __restrict__ Kimg,
               char* __restrict__ S, int b0, int s0) {
  __shared__ _Float16 sMem[65536];  // 128 KiB: 8 x 16KB half-tile slots
  const int tid = threadIdx.x;
  const int wave = tid >> 6, lane = tid & 63;
  const int quad = lane >> 4, lr = lane & 15;
  const int wm = wave >> 2, wn = wave & 3;               // 2 x 4 wave grid
  const int cb = blockIdx.x;                             // 256-col t-block 0..15
  const int rbL = blockIdx.z * gridDim.y + blockIdx.y;   // 256-row chunk block
  const int b = b0 + blockIdx.z;
  const int qrb = (s0 >> 7) + blockIdx.y * 2;            // Q 128-row block base

  const char* Ab0 = Qimg + ((size_t)((b * 32 + qrb) * 8)) * 16384;
  const char* Ab1 = Ab0 + 8 * 16384;
  const char* Bb0 = Kimg + ((size_t)((b * 32 + cb * 2) * 8)) * 16384;
  const char* Bb1 = Bb0 + 8 * 16384;

  _Float16* const sBslot = sMem + (wn >> 1) * 8192;      // + parity*32768
  _Float16* const sAslot = sMem + (2 + wm) * 8192;       // + parity*32768
  const int arow = lr;                                   // + mh*64 + rt*16
  const int bcol = (wn & 1) * 64 + lr;                   // + ct*16
  const int sw = lr & 7;

  // prologue: tile0 {B0,B1,A0,A1} -> slots 0-3; tile1 {B0,B1,A0} -> slots 4-6
  STAGE(Bb0, 0); STAGE(Bb1, 1); STAGE(Ab0, 2); STAGE(Ab1, 3);
  asm volatile("s_waitcnt vmcnt(4)" ::: "memory");
  STAGE(Bb0 + 16384, 4); STAGE(Bb1 + 16384, 5); STAGE(Ab0 + 16384, 6);
  asm volatile("s_waitcnt vmcnt(6)" ::: "memory");  // tile0 fully resident
  __builtin_amdgcn_s_barrier();
  __builtin_amdgcn_sched_barrier(0);

  f4 acc[2][2][4][2];
#pragma unroll
  for (int i = 0; i < 2; ++i)
#pragma unroll
    for (int j = 0; j < 2; ++j)
#pragma unroll
      for (int rt = 0; rt < 4; ++rt)
#pragma unroll
        for (int ct = 0; ct < 2; ++ct) { f4 zz = {0.f, 0.f, 0.f, 0.f}; acc[i][j][rt][ct] = zz; }
  h8 a[4][2], bb[4][2];

#pragma unroll
  for (int kt = 0; kt < 8; ++kt) {
    const int sb = (kt & 1) * 32768;  // parity element offset (4 slots x 8192)

    // ---- phase 0: ds-read A(mh0) + ALL B; stage (kt+1).A1; MFMA q(0,0)
#pragma unroll
    for (int rt = 0; rt < 4; ++rt)
#pragma unroll
      for (int ks = 0; ks < 2; ++ks)
        a[rt][ks] = *(const h8*)&sAslot[sb + (rt * 16 + arow) * 64 + (((ks * 4 + quad) ^ sw) << 3)];
#pragma unroll
    for (int ct = 0; ct < 4; ++ct)
#pragma unroll
      for (int ks = 0; ks < 2; ++ks)
        bb[ct][ks] = *(const h8*)&sBslot[sb + (ct * 16 + bcol) * 64 + (((ks * 4 + quad) ^ sw) << 3)];
    if (kt < 7) { STAGE(Ab1 + (kt + 1) * 16384, ((kt + 1) & 1) * 4 + 3); }
    __builtin_amdgcn_s_barrier();
    asm volatile("s_waitcnt lgkmcnt(0)" ::: "memory");
    __builtin_amdgcn_sched_barrier(0);
    __builtin_amdgcn_s_setprio(1);
#pragma unroll
    for (int rt = 0; rt < 4; ++rt)
#pragma unroll
      for (int ct = 0; ct < 2; ++ct)
#pragma unroll
        for (int ks = 0; ks < 2; ++ks)
          acc[0][0][rt][ct] = MFMA16(a[rt][ks], bb[ct][ks], acc[0][0][rt][ct]);
    __builtin_amdgcn_s_setprio(0);
    __builtin_amdgcn_s_barrier();

    // ---- phase 1: stage (kt+2).B0 (B slots free after ph0); MFMA q(0,1)
    if (kt < 6) { STAGE(Bb0 + (kt + 2) * 16384, (kt & 1) * 4 + 0); }
    __builtin_amdgcn_s_barrier();
    __builtin_amdgcn_s_setprio(1);
#pragma unroll
    for (int rt = 0; rt < 4; ++rt)
#pragma unroll
      for (int ct = 0; ct < 2; ++ct)
#pragma unroll
        for (int ks = 0; ks < 2; ++ks)
          acc[0][1][rt][ct] = MFMA16(a[rt][ks], bb[2 + ct][ks], acc[0][1][rt][ct]);
    __builtin_amdgcn_s_setprio(0);
    __builtin_amdgcn_s_barrier();

    // ---- phase 2: ds-read A(mh1); stage (kt+2).B1; MFMA q(1,0)
#pragma unroll
    for (int rt = 0; rt < 4; ++rt)
#pragma unroll
      for (int ks = 0; ks < 2; ++ks)
        a[rt][ks] = *(const h8*)&sAslot[sb + (64 + rt * 16 + arow) * 64 + (((ks * 4 + quad) ^ sw) << 3)];
    if (kt < 6) { STAGE(Bb1 + (kt + 2) * 16384, (kt & 1) * 4 + 1); }
    __builtin_amdgcn_s_barrier();
    asm volatile("s_waitcnt lgkmcnt(0)" ::: "memory");
    __builtin_amdgcn_sched_barrier(0);
    __builtin_amdgcn_s_setprio(1);
#pragma unroll
    for (int rt = 0; rt < 4; ++rt)
#pragma unroll
      for (int ct = 0; ct < 2; ++ct)
#pragma unroll
        for (int ks = 0; ks < 2; ++ks)
          acc[1][0][rt][ct] = MFMA16(a[rt][ks], bb[ct][ks], acc[1][0][rt][ct]);
    __builtin_amdgcn_s_setprio(0);
    __builtin_amdgcn_s_barrier();

    // ---- phase 3: stage (kt+2).A0 (A slots free after ph2); MFMA q(1,1); boundary vmcnt
    if (kt < 6) { STAGE(Ab0 + (kt + 2) * 16384, (kt & 1) * 4 + 2); }
    __builtin_amdgcn_s_barrier();
    __builtin_amdgcn_s_setprio(1);
#pragma unroll
    for (int rt = 0; rt < 4; ++rt)
#pragma unroll
      for (int ct = 0; ct < 2; ++ct)
#pragma unroll
        for (int ks = 0; ks < 2; ++ks)
          acc[1][1][rt][ct] = MFMA16(a[rt][ks], bb[2 + ct][ks], acc[1][1][rt][ct]);
    __builtin_amdgcn_s_setprio(0);
    if (kt < 6) {
      asm volatile("s_waitcnt vmcnt(6)" ::: "memory");  // tile kt+1 resident; 3 HTs in flight
    } else if (kt == 6) {
      asm volatile("s_waitcnt vmcnt(0)" ::: "memory");  // epilogue drain
    }
    __builtin_amdgcn_s_barrier();
    __builtin_amdgcn_sched_barrier(0);
  }

  // ---- epilogue: fp16 stash in Simg layout across whole 128KB LDS -> coalesced stores
  __syncthreads();
  _Float16* sC = sMem;
#pragma unroll
  for (int mh = 0; mh < 2; ++mh)
#pragma unroll
    for (int nh = 0; nh < 2; ++nh)
#pragma unroll
      for (int rt = 0; rt < 4; ++rt)
#pragma unroll
        for (int ct = 0; ct < 2; ++ct)
#pragma unroll
          for (int rr = 0; rr < 4; ++rr) {
            const int row = wm * 128 + mh * 64 + rt * 16 + quad * 4 + rr;  // 0..255
            const int col = wn * 64 + nh * 32 + ct * 16 + lr;              // 0..255
            const int ib = ((row >> 7) << 2) + (col >> 6);
            const int rw = row & 127, kk = col & 63;
            sC[ib * 8192 + rw * 64 + ((((kk >> 3) & 7) ^ (rw & 7)) << 3) + (kk & 7)] =
                (_Float16)acc[mh][nh][rt][ct][rr];
          }
  __syncthreads();
  const int ib = tid >> 6, tl_ = tid & 63;
  char* dst = S + ((size_t)((rbL * 2 + (ib >> 2)) * 64 + cb * 4 + (ib & 3))) * 16384;
#pragma unroll
  for (int r2 = 0; r2 < 2; ++r2)
#pragma unroll
    for (int k = 0; k < 8; ++k)
      *(int4*)(dst + (tl_ * 2 + r2) * 128 + k * 16) =
          *(const int4*)&sC[ib * 8192 + (tl_ * 2 + r2) * 64 + k * 8];
}
#undef STAGE

// ---------------- ML: rowmax, P = exp(S-m) in place, linv ----------------
__global__ __launch_bounds__(256, 2)
void ml_kernel(char* __restrict__ S, float* __restrict__ linv, int b0, int s0, int msLog) {
  const int tid = threadIdx.x;
  const int wave = tid >> 6, lane = tid & 63;
  const int r = blockIdx.x * 4 + wave;  // chunk row
  const int rbL = r >> 7, rl = r & 127;
  char* base = S + ((size_t)(rbL * 64 + lane)) * 16384 + (size_t)rl * 128;
  h8 v[8];
#pragma unroll
  for (int k = 0; k < 8; ++k) v[k] = *(const h8*)(base + k * 16);
  float m = -3.0e38f;
#pragma unroll
  for (int k = 0; k < 8; ++k)
#pragma unroll
    for (int j = 0; j < 8; ++j) m = fmaxf(m, (float)v[k][j]);
  m = fmaxf(m, __shfl_xor(m, 1));
  m = fmaxf(m, __shfl_xor(m, 2));
  m = fmaxf(m, __shfl_xor(m, 4));
  m = fmaxf(m, __shfl_xor(m, 8));
  m = fmaxf(m, __shfl_xor(m, 16));
  m = fmaxf(m, __shfl_xor(m, 32));
  float s = 0.f;
#pragma unroll
  for (int k = 0; k < 8; ++k)
#pragma unroll
    for (int j = 0; j < 8; ++j) {
      float e = __expf((float)v[k][j] - m);
      v[k][j] = (_Float16)e;
      s += e;
    }
#pragma unroll
  for (int k = 0; k < 8; ++k) *(h8*)(base + k * 16) = v[k];
  s += __shfl_xor(s, 1);
  s += __shfl_xor(s, 2);
  s += __shfl_xor(s, 4);
  s += __shfl_xor(s, 8);
  s += __shfl_xor(s, 16);
  s += __shfl_xor(s, 32);
  if (lane == 0) {
    const int bL = r >> msLog, sloc = r & ((1 << msLog) - 1);
    linv[(b0 + bL) * 4096 + s0 + sloc] = 1.0f / s;
  }
}

// ---------------- PV GEMM: O[s][d] = P . V (64x128 tiles, K=4096) ----------------
__global__ __launch_bounds__(256, 4)
void pv_kernel(const char* __restrict__ S, const char* __restrict__ VTimg,
               const float* __restrict__ linv, float* __restrict__ out, int b0, int s0) {
  __shared__ _Float16 sMem[12288];  // sA 4096 (8KB) + sB 8192 (16KB)
  _Float16* sA = sMem;
  _Float16* sB = sMem + 4096;
  const int tid = threadIdx.x;
  const int wave = tid >> 6, lane = tid & 63;
  const int quad = lane >> 4, lr = lane & 15;
  const int db = blockIdx.x;                            // 0..3
  const int sbL = blockIdx.z * gridDim.y + blockIdx.y;  // chunk 64-row block
  const int b = b0 + blockIdx.z;
  const int rbase = (wave & 1) * 32, cbase = (wave >> 1) * 64;
  const char* Ab = S + ((size_t)((sbL >> 1) * 64)) * 16384 + (size_t)(sbL & 1) * 8192;
  const char* Bb = VTimg + ((size_t)((b * 4 + db) * 64)) * 16384;

  f4 acc[2][4];
#pragma unroll
  for (int i = 0; i < 2; ++i)
#pragma unroll
    for (int j = 0; j < 4; ++j) { f4 zz = {0.f, 0.f, 0.f, 0.f}; acc[i][j] = zz; }

  {  // stage(0)
#pragma unroll
    for (int j = 0; j < 2; ++j)
      gl_lds16(Ab + tid * 16 + j * 4096, (char*)sA + tid * 16 + j * 4096);
#pragma unroll
    for (int j = 0; j < 4; ++j)
      gl_lds16(Bb + tid * 16 + j * 4096, (char*)sB + tid * 16 + j * 4096);
  }

  for (int kt = 0; kt < 64; ++kt) {
    __syncthreads();  // DRAIN
#pragma unroll
    for (int ks = 0; ks < 2; ++ks) {
      h8 a[2], bb[4];
#pragma unroll
      for (int rt = 0; rt < 2; ++rt) {
        const int r = rbase + rt * 16 + lr;
        a[rt] = *(const h8*)&sA[r * 64 + ((((ks << 2) | quad) ^ (lr & 7)) << 3)];
      }
#pragma unroll
      for (int ct = 0; ct < 4; ++ct) {
        const int r = cbase + ct * 16 + lr;
        bb[ct] = *(const h8*)&sB[r * 64 + ((((ks << 2) | quad) ^ (lr & 7)) << 3)];
      }
#pragma unroll
      for (int rt = 0; rt < 2; ++rt)
#pragma unroll
        for (int ct = 0; ct < 4; ++ct)
          acc[rt][ct] = MFMA16(a[rt], bb[ct], acc[rt][ct]);
    }
    __syncthreads();  // FREE
    if (kt < 63) {
#pragma unroll
      for (int j = 0; j < 2; ++j)
        gl_lds16(Ab + (kt + 1) * 16384 + tid * 16 + j * 4096, (char*)sA + tid * 16 + j * 4096);
#pragma unroll
      for (int j = 0; j < 4; ++j)
        gl_lds16(Bb + (kt + 1) * 16384 + tid * 16 + j * 4096, (char*)sB + tid * 16 + j * 4096);
    }
  }

  // epilogue: x linv, scatter stores (64B segments per quad)
#pragma unroll
  for (int rt = 0; rt < 2; ++rt) {
#pragma unroll
    for (int r = 0; r < 4; ++r) {
      const int srow = s0 + blockIdx.y * 64 + rbase + rt * 16 + quad * 4 + r;
      const float li = linv[b * 4096 + srow];
      float* op = &out[((size_t)b * 4096 + srow) * 512 + db * 128];
#pragma unroll
      for (int ct = 0; ct < 4; ++ct)
        op[cbase + ct * 16 + lr] = acc[rt][ct][r] * li;
    }
  }
}

extern "C" void kernel_launch(void* const* d_in, const int* in_sizes, int n_in,
                              void* d_out, int out_size, void* d_ws, size_t ws_size,
                              hipStream_t stream) {
  (void)in_sizes; (void)n_in; (void)out_size;
  const float* x  = (const float*)d_in[0];
  const float* Wq = (const float*)d_in[1];
  const float* bq = (const float*)d_in[2];
  const float* Wk = (const float*)d_in[3];
  const float* bk = (const float*)d_in[4];
  const float* Wv = (const float*)d_in[5];
  const float* bv = (const float*)d_in[6];
  float* out = (float*)d_out;
  char* ws = (char*)d_ws;
  char* Qimg  = ws;
  char* Kimg  = ws + ((size_t)16 << 20);
  char* VTimg = ws + ((size_t)32 << 20);
  _Float16* Wt = (_Float16*)(ws + ((size_t)48 << 20));           // 1.5MB
  float* linv  = (float*)(ws + ((size_t)50 << 20) - 65536);      // 64KB
  char* Simg   = ws + ((size_t)50 << 20);

  wconv_kernel<<<dim3(384), dim3(256), 0, stream>>>(Wq, Wk, Wv, Wt);
  proj_kernel<<<dim3(128, 4, 3), dim3(256), 0, stream>>>(x, Wt, bq, bk, bv, Qimg, Kimg, VTimg);

  // chunk ladder on ws_size (constant per deployment -> same work every call)
  const size_t avail = ws_size > ((size_t)50 << 20) ? ws_size - ((size_t)50 << 20) : 0;
  int nchunk, nb, Ms;
  if      (avail >= ((size_t)128 << 20)) { nchunk = 1;  nb = 4; Ms = 4096; }
  else if (avail >= ((size_t)64  << 20)) { nchunk = 2;  nb = 2; Ms = 4096; }
  else if (avail >= ((size_t)32  << 20)) { nchunk = 4;  nb = 1; Ms = 4096; }
  else if (avail >= ((size_t)16  << 20)) { nchunk = 8;  nb = 1; Ms = 2048; }
  else if (avail >= ((size_t)8   << 20)) { nchunk = 16; nb = 1; Ms = 1024; }
  else                                   { nchunk = 32; nb = 1; Ms = 512;  }
  int msLog = 31 - __builtin_clz(Ms);
  const int chunksPerBatch = 4096 / Ms;  // for nb==1 paths; nb>1 has Ms=4096

  for (int c = 0; c < nchunk; ++c) {
    int b0, s0;
    if (nb > 1 || Ms == 4096) { b0 = c * nb; s0 = 0; }
    else { b0 = c / chunksPerBatch; s0 = (c % chunksPerBatch) * Ms; }
    qk_kernel<<<dim3(16, Ms / 256, nb), dim3(512), 0, stream>>>(Qimg, Kimg, Simg, b0, s0);
    ml_kernel<<<dim3(nb * Ms / 4), dim3(256), 0, stream>>>(Simg, linv, b0, s0, msLog);
    pv_kernel<<<dim3(4, Ms / 64, nb), dim3(256), 0, stream>>>(Simg, VTimg, linv, out, b0, s0);
  }
}

// Round 3
// 375.927 us; speedup vs baseline: 1.1416x; 1.1416x over previous
//
#include <hip/hip_runtime.h>

typedef _Float16 h8 __attribute__((ext_vector_type(8)));
typedef float f4 __attribute__((ext_vector_type(4)));

#define MFMA16(a, b, c) __builtin_amdgcn_mfma_f32_16x16x32_f16((a), (b), (c), 0, 0, 0)

__device__ static inline void gl_lds16(const void* g, void* l) {
  __builtin_amdgcn_global_load_lds((const __attribute__((address_space(1))) unsigned int*)g,
                                   (__attribute__((address_space(3))) unsigned int*)l, 16, 0, 0);
}

// Monotone float<->uint encoding for atomicMax on floats (any sign).
__device__ static inline unsigned encf(float f) {
  unsigned u = __float_as_uint(f);
  return (u & 0x80000000u) ? ~u : (u | 0x80000000u);
}
__device__ static inline float decf(unsigned u) {
  return __uint_as_float((u & 0x80000000u) ? (u ^ 0x80000000u) : ~u);
}

// B=4, S=4096, D=512.
// IMG block = 16KB = 128 rows x 64 k fp16; half-offset(r,k) = r*64 + ((((k>>3)&7)^(r&7))<<3) + (k&7).
// XOR-8 swizzle baked in global so linear global_load_lds staging yields bank-floor ds_read_b128 frags.
//  Qimg/Kimg: block(b, rb=s>>7, kc=d>>6) at ((b*32+rb)*8+kc)*16KB        [16MB each]
//  VTimg:     block(b, rb=d>>7, kc=s>>6) at ((b*4+rb)*64+kc)*16KB        [16MB]
//  Wt:        block(z, rb=n>>7, kc=k>>6) at ((z*4+rb)*8+kc)*16KB         [1.5MB]
//  Simg(chunk): block(rbL, kc=t>>6) at (rbL*64+kc)*16KB, rbL = chunk-row>>7
// Softmax fused: qk atomically max-reduces rows into mEnc[]; pv exps A-tiles while
// staging (direct h8 loads, NO type-punned locals) and owns complete row-sums (K=4096).

// ---------------- weight convert (+ mEnc zero) ----------------
__global__ void wconv_kernel(const float* __restrict__ Wq, const float* __restrict__ Wk,
                             const float* __restrict__ Wv, _Float16* __restrict__ Wt,
                             unsigned* __restrict__ mEnc) {
  int idx = blockIdx.x * 256 + threadIdx.x;
  if (idx < 16384) mEnc[idx] = 0u;  // enc floor (< enc of any finite float)
  int z = idx >> 15, rem = idx & 32767;
  int n = rem >> 6, k0 = (rem & 63) << 3;
  const float* W = (z == 0) ? Wq : (z == 1) ? Wk : Wv;
  float sc = (z == 0) ? 0.5f : 1.0f;
  h8 v;
#pragma unroll
  for (int j = 0; j < 8; ++j) v[j] = (_Float16)(W[(k0 + j) * 512 + n] * sc);
  size_t blk = (size_t)((z * 4 + (n >> 7)) * 8 + (k0 >> 6));
  int off = (n & 127) * 64 + ((((k0 >> 3) & 7) ^ (n & 7)) << 3);
  *(h8*)&Wt[blk * 8192 + off] = v;
}

// ---------------- QKV projection -> images ----------------
__global__ __launch_bounds__(256, 3)
void proj_kernel(const float* __restrict__ x, const _Float16* __restrict__ Wt,
                 const float* __restrict__ bq, const float* __restrict__ bk,
                 const float* __restrict__ bv,
                 char* __restrict__ Qimg, char* __restrict__ Kimg, char* __restrict__ VTimg) {
  __shared__ _Float16 sMem[16384];  // sA 8192 + sB 8192; epilogue stash 16384
  _Float16* sA = sMem;
  _Float16* sB = sMem + 8192;
  const int tid = threadIdx.x;
  const int wave = tid >> 6, lane = tid & 63;
  const int quad = lane >> 4, lr = lane & 15;
  const int mbase = blockIdx.x * 128, nbase = blockIdx.y * 128, z = blockIdx.z;
  const int sr = tid >> 1, sseg = tid & 1;
  const int rbase = (wave & 1) * 64, cbase = (wave >> 1) * 64;
  const char* WtB = (const char*)Wt + ((size_t)(z * 4 + (nbase >> 7)) * 8) * 16384;

  float4 ax[8];
  f4 acc[4][4];
#pragma unroll
  for (int i = 0; i < 4; ++i)
#pragma unroll
    for (int j = 0; j < 4; ++j) { f4 zz = {0.f, 0.f, 0.f, 0.f}; acc[i][j] = zz; }

  {  // preload ax(0), stage B(0)
    const float4* asrc = (const float4*)&x[(size_t)(mbase + sr) * 512 + sseg * 32];
#pragma unroll
    for (int i = 0; i < 8; ++i) ax[i] = asrc[i];
#pragma unroll
    for (int j = 0; j < 4; ++j)
      gl_lds16(WtB + tid * 16 + j * 4096, (char*)sB + tid * 16 + j * 4096);
  }

  for (int kt = 0; kt < 8; ++kt) {
    if (kt > 0) __syncthreads();  // FREE: readers of kt-1 done
    // sA(kt) from ax (fp32->fp16, swizzled)
#pragma unroll
    for (int i = 0; i < 4; ++i) {
      h8 v;
      float4 f0 = ax[2 * i], f1 = ax[2 * i + 1];
      v[0] = (_Float16)f0.x; v[1] = (_Float16)f0.y; v[2] = (_Float16)f0.z; v[3] = (_Float16)f0.w;
      v[4] = (_Float16)f1.x; v[5] = (_Float16)f1.y; v[6] = (_Float16)f1.z; v[7] = (_Float16)f1.w;
      *(h8*)&sA[sr * 64 + (((sseg * 4 + i) ^ (sr & 7)) << 3)] = v;
    }
    if (kt > 0) {  // stage B(kt)
#pragma unroll
      for (int j = 0; j < 4; ++j)
        gl_lds16(WtB + kt * 16384 + tid * 16 + j * 4096, (char*)sB + tid * 16 + j * 4096);
    }
    __syncthreads();  // DRAIN
    if (kt < 7) {
      const float4* asrc = (const float4*)&x[(size_t)(mbase + sr) * 512 + (kt + 1) * 64 + sseg * 32];
#pragma unroll
      for (int i = 0; i < 8; ++i) ax[i] = asrc[i];
    }
#pragma unroll
    for (int ks = 0; ks < 2; ++ks) {
      h8 a[4], bb[4];
#pragma unroll
      for (int rt = 0; rt < 4; ++rt) {
        const int r = rbase + rt * 16 + lr;
        a[rt] = *(const h8*)&sA[r * 64 + ((((ks << 2) | quad) ^ (lr & 7)) << 3)];
      }
#pragma unroll
      for (int ct = 0; ct < 4; ++ct) {
        const int r = cbase + ct * 16 + lr;
        bb[ct] = *(const h8*)&sB[r * 64 + ((((ks << 2) | quad) ^ (lr & 7)) << 3)];
      }
#pragma unroll
      for (int rt = 0; rt < 4; ++rt)
#pragma unroll
        for (int ct = 0; ct < 4; ++ct)
          acc[rt][ct] = MFMA16(a[rt], bb[ct], acc[rt][ct]);
    }
  }

  // ---- epilogue: swizzled stash -> coalesced image stores ----
  const float* bias = (z == 0) ? bq : (z == 1) ? bk : bv;
  const float bscale = (z == 0) ? 0.5f : 1.0f;
  _Float16* sC = sMem;
  __syncthreads();
#pragma unroll
  for (int ct = 0; ct < 4; ++ct) {
    const int dl = cbase + ct * 16 + lr;
    const float bb = bias[nbase + dl] * bscale;
#pragma unroll
    for (int rt = 0; rt < 4; ++rt) {
#pragma unroll
      for (int r = 0; r < 4; ++r) {
        const int sl = rbase + rt * 16 + quad * 4 + r;
        const _Float16 val = (_Float16)(acc[rt][ct][r] + bb);
        if (z == 2) {  // VT: row=d, k=s
          sC[((sl >> 6) << 13) + dl * 64 + ((((sl >> 3) & 7) ^ (dl & 7)) << 3) + (sl & 7)] = val;
        } else {       // Q/K: row=s, k=d
          sC[((dl >> 6) << 13) + sl * 64 + ((((dl >> 3) & 7) ^ (sl & 7)) << 3) + (dl & 7)] = val;
        }
      }
    }
  }
  __syncthreads();
  const int b_ = mbase >> 12;
  char* dst;
  if (z != 2) {
    char* img = (z == 0) ? Qimg : Kimg;
    dst = img + ((size_t)((b_ * 32 + ((mbase & 4095) >> 7)) * 8 + (nbase >> 6) + (tid >> 7))) * 16384;
  } else {
    dst = VTimg + ((size_t)((b_ * 4 + (nbase >> 7)) * 64 + ((mbase & 4095) >> 6) + (tid >> 7))) * 16384;
  }
  dst += (size_t)(tid & 127) * 128;
#pragma unroll
  for (int k = 0; k < 8; ++k)
    *(int4*)(dst + k * 16) = *(const int4*)&sC[tid * 64 + k * 8];
}

// ---------------- QK GEMM: S[s][t] = Q . K^T -> Simg chunk (+ row-max atomics) ----------------
__global__ __launch_bounds__(256, 3)
void qk_kernel(const char* __restrict__ Qimg, const char* __restrict__ Kimg,
               char* __restrict__ S, unsigned* __restrict__ mEnc, int b0, int s0) {
  __shared__ _Float16 sMem[16384];
  _Float16* sA = sMem;
  _Float16* sB = sMem + 8192;
  const int tid = threadIdx.x;
  const int wave = tid >> 6, lane = tid & 63;
  const int quad = lane >> 4, lr = lane & 15;
  const int cb = blockIdx.x;                               // t-block 0..31
  const int rbL = blockIdx.z * gridDim.y + blockIdx.y;     // chunk row-block
  const int b = b0 + blockIdx.z;
  const int rbase = (wave & 1) * 64, cbase = (wave >> 1) * 64;
  const char* Ab = Qimg + ((size_t)((b * 32 + (s0 >> 7) + blockIdx.y) * 8)) * 16384;
  const char* Bb = Kimg + ((size_t)((b * 32 + cb) * 8)) * 16384;

  f4 acc[4][4];
#pragma unroll
  for (int i = 0; i < 4; ++i)
#pragma unroll
    for (int j = 0; j < 4; ++j) { f4 zz = {0.f, 0.f, 0.f, 0.f}; acc[i][j] = zz; }

#pragma unroll
  for (int j = 0; j < 4; ++j) {  // stage(0)
    gl_lds16(Ab + tid * 16 + j * 4096, (char*)sA + tid * 16 + j * 4096);
    gl_lds16(Bb + tid * 16 + j * 4096, (char*)sB + tid * 16 + j * 4096);
  }

  for (int kt = 0; kt < 8; ++kt) {
    __syncthreads();  // DRAIN stage(kt)
#pragma unroll
    for (int ks = 0; ks < 2; ++ks) {
      h8 a[4], bb[4];
#pragma unroll
      for (int rt = 0; rt < 4; ++rt) {
        const int r = rbase + rt * 16 + lr;
        a[rt] = *(const h8*)&sA[r * 64 + ((((ks << 2) | quad) ^ (lr & 7)) << 3)];
      }
#pragma unroll
      for (int ct = 0; ct < 4; ++ct) {
        const int r = cbase + ct * 16 + lr;
        bb[ct] = *(const h8*)&sB[r * 64 + ((((ks << 2) | quad) ^ (lr & 7)) << 3)];
      }
#pragma unroll
      for (int rt = 0; rt < 4; ++rt)
#pragma unroll
        for (int ct = 0; ct < 4; ++ct)
          acc[rt][ct] = MFMA16(a[rt], bb[ct], acc[rt][ct]);
    }
    __syncthreads();  // FREE
    if (kt < 7) {
#pragma unroll
      for (int j = 0; j < 4; ++j) {
        gl_lds16(Ab + (kt + 1) * 16384 + tid * 16 + j * 4096, (char*)sA + tid * 16 + j * 4096);
        gl_lds16(Bb + (kt + 1) * 16384 + tid * 16 + j * 4096, (char*)sB + tid * 16 + j * 4096);
      }
    }
  }

  // ---- row-max partials over this block's 128 cols -> encoded atomicMax ----
  {
    const int growb = b * 4096 + s0 + blockIdx.y * 128;
#pragma unroll
    for (int rt = 0; rt < 4; ++rt) {
#pragma unroll
      for (int r = 0; r < 4; ++r) {
        float mx = fmaxf(fmaxf(acc[rt][0][r], acc[rt][1][r]),
                         fmaxf(acc[rt][2][r], acc[rt][3][r]));
        mx = fmaxf(mx, __shfl_xor(mx, 1));
        mx = fmaxf(mx, __shfl_xor(mx, 2));
        mx = fmaxf(mx, __shfl_xor(mx, 4));
        mx = fmaxf(mx, __shfl_xor(mx, 8));
        if (lr == 0)
          atomicMax(&mEnc[growb + rbase + rt * 16 + quad * 4 + r], encf(mx));
      }
    }
  }

  // epilogue: fp16 stash in Simg layout -> coalesced stores
  _Float16* sC = sMem;
#pragma unroll
  for (int ct = 0; ct < 4; ++ct) {
    const int tl = cbase + ct * 16 + lr;
#pragma unroll
    for (int rt = 0; rt < 4; ++rt) {
#pragma unroll
      for (int r = 0; r < 4; ++r) {
        const int sl = rbase + rt * 16 + quad * 4 + r;
        sC[((tl >> 6) << 13) + sl * 64 + ((((tl >> 3) & 7) ^ (sl & 7)) << 3) + (tl & 7)] =
            (_Float16)acc[rt][ct][r];
      }
    }
  }
  __syncthreads();
  char* dst = S + ((size_t)(rbL * 64 + cb * 2 + (tid >> 7))) * 16384 + (size_t)(tid & 127) * 128;
#pragma unroll
  for (int k = 0; k < 8; ++k)
    *(int4*)(dst + k * 16) = *(const int4*)&sC[tid * 64 + k * 8];
}

// ---------------- PV GEMM with fused exp + rowsum: O = softmax(S) . V ----------------
// A-tile exp-staged with DIRECT h8 loads (no punned locals); each block covers its
// rows' FULL K=4096 -> complete local rowsums, no ml pass, no linv global traffic.
__global__ __launch_bounds__(256, 4)
void pv_kernel(const char* __restrict__ S, const char* __restrict__ VTimg,
               const unsigned* __restrict__ mEnc, float* __restrict__ out, int b0, int s0) {
  __shared__ _Float16 sMem[12288];  // sA 4096 (8KB) + sB 8192 (16KB)
  __shared__ float ls[64];          // per-row denominator
  _Float16* sA = sMem;
  _Float16* sB = sMem + 4096;
  const int tid = threadIdx.x;
  const int wave = tid >> 6, lane = tid & 63;
  const int quad = lane >> 4, lr = lane & 15;
  const int db = blockIdx.x;                            // 0..3
  const int sbL = blockIdx.z * gridDim.y + blockIdx.y;  // chunk 64-row block
  const int b = b0 + blockIdx.z;
  const int rbase = (wave & 1) * 32, cbase = (wave >> 1) * 64;
  const char* Ab = S + ((size_t)((sbL >> 1) * 64)) * 16384 + (size_t)(sbL & 1) * 8192;
  const char* Bb = VTimg + ((size_t)((b * 4 + db) * 64)) * 16384;

  // this thread's two staged rows (16B chunk at tid*16 -> row tid>>3; +4096B -> +32)
  const int lrow = tid >> 3;
  const int growb = b * 4096 + s0 + blockIdx.y * 64;
  const float m0 = decf(mEnc[growb + lrow]);
  const float m1 = decf(mEnc[growb + 32 + lrow]);
  float rs0 = 0.f, rs1 = 0.f;

  f4 acc[2][4];
#pragma unroll
  for (int i = 0; i < 2; ++i)
#pragma unroll
    for (int j = 0; j < 4; ++j) { f4 zz = {0.f, 0.f, 0.f, 0.f}; acc[i][j] = zz; }

  {  // prologue: B(0) gl_lds; A(0) direct h8 load -> exp -> sA
#pragma unroll
    for (int j = 0; j < 4; ++j)
      gl_lds16(Bb + tid * 16 + j * 4096, (char*)sB + tid * 16 + j * 4096);
    {
      h8 ha = *(const h8*)(Ab + tid * 16);
      h8 w;
#pragma unroll
      for (int u = 0; u < 8; ++u) { float e = __expf((float)ha[u] - m0); w[u] = (_Float16)e; rs0 += e; }
      *(h8*)((char*)sA + tid * 16) = w;
    }
    {
      h8 ha = *(const h8*)(Ab + tid * 16 + 4096);
      h8 w;
#pragma unroll
      for (int u = 0; u < 8; ++u) { float e = __expf((float)ha[u] - m1); w[u] = (_Float16)e; rs1 += e; }
      *(h8*)((char*)sA + tid * 16 + 4096) = w;
    }
  }

  for (int kt = 0; kt < 64; ++kt) {
    __syncthreads();  // DRAIN: sA(kt)/sB(kt) resident
#pragma unroll
    for (int ks = 0; ks < 2; ++ks) {
      h8 a[2], bb[4];
#pragma unroll
      for (int rt = 0; rt < 2; ++rt) {
        const int r = rbase + rt * 16 + lr;
        a[rt] = *(const h8*)&sA[r * 64 + ((((ks << 2) | quad) ^ (lr & 7)) << 3)];
      }
#pragma unroll
      for (int ct = 0; ct < 4; ++ct) {
        const int r = cbase + ct * 16 + lr;
        bb[ct] = *(const h8*)&sB[r * 64 + ((((ks << 2) | quad) ^ (lr & 7)) << 3)];
      }
#pragma unroll
      for (int rt = 0; rt < 2; ++rt)
#pragma unroll
        for (int ct = 0; ct < 4; ++ct)
          acc[rt][ct] = MFMA16(a[rt], bb[ct], acc[rt][ct]);
    }
    __syncthreads();  // FREE: sA/sB(kt) readers done
    if (kt < 63) {
#pragma unroll
      for (int j = 0; j < 4; ++j)
        gl_lds16(Bb + (kt + 1) * 16384 + tid * 16 + j * 4096, (char*)sB + tid * 16 + j * 4096);
      {
        h8 ha = *(const h8*)(Ab + (kt + 1) * 16384 + tid * 16);
        h8 w;
#pragma unroll
        for (int u = 0; u < 8; ++u) { float e = __expf((float)ha[u] - m0); w[u] = (_Float16)e; rs0 += e; }
        *(h8*)((char*)sA + tid * 16) = w;
      }
      {
        h8 ha = *(const h8*)(Ab + (kt + 1) * 16384 + tid * 16 + 4096);
        h8 w;
#pragma unroll
        for (int u = 0; u < 8; ++u) { float e = __expf((float)ha[u] - m1); w[u] = (_Float16)e; rs1 += e; }
        *(h8*)((char*)sA + tid * 16 + 4096) = w;
      }
    }
  }

  // rowsum: reduce across the 8 threads sharing each staged row, publish via LDS
  rs0 += __shfl_xor(rs0, 1); rs0 += __shfl_xor(rs0, 2); rs0 += __shfl_xor(rs0, 4);
  rs1 += __shfl_xor(rs1, 1); rs1 += __shfl_xor(rs1, 2); rs1 += __shfl_xor(rs1, 4);
  if ((tid & 7) == 0) { ls[lrow] = rs0; ls[32 + lrow] = rs1; }
  __syncthreads();

  // epilogue: x 1/rowsum, scatter stores (64B segments per quad)
#pragma unroll
  for (int rt = 0; rt < 2; ++rt) {
#pragma unroll
    for (int r = 0; r < 4; ++r) {
      const int lrw = rbase + rt * 16 + quad * 4 + r;
      const int srow = s0 + blockIdx.y * 64 + lrw;
      const float li = 1.0f / ls[lrw];
      float* op = &out[((size_t)b * 4096 + srow) * 512 + db * 128];
#pragma unroll
      for (int ct = 0; ct < 4; ++ct)
        op[cbase + ct * 16 + lr] = acc[rt][ct][r] * li;
    }
  }
}

extern "C" void kernel_launch(void* const* d_in, const int* in_sizes, int n_in,
                              void* d_out, int out_size, void* d_ws, size_t ws_size,
                              hipStream_t stream) {
  (void)in_sizes; (void)n_in; (void)out_size;
  const float* x  = (const float*)d_in[0];
  const float* Wq = (const float*)d_in[1];
  const float* bq = (const float*)d_in[2];
  const float* Wk = (const float*)d_in[3];
  const float* bk = (const float*)d_in[4];
  const float* Wv = (const float*)d_in[5];
  const float* bv = (const float*)d_in[6];
  float* out = (float*)d_out;
  char* ws = (char*)d_ws;
  char* Qimg  = ws;
  char* Kimg  = ws + ((size_t)16 << 20);
  char* VTimg = ws + ((size_t)32 << 20);
  _Float16* Wt = (_Float16*)(ws + ((size_t)48 << 20));            // 1.5MB
  unsigned* mEnc = (unsigned*)(ws + ((size_t)50 << 20) - 65536);  // 64KB row-max
  char* Simg   = ws + ((size_t)50 << 20);

  wconv_kernel<<<dim3(384), dim3(256), 0, stream>>>(Wq, Wk, Wv, Wt, mEnc);
  proj_kernel<<<dim3(128, 4, 3), dim3(256), 0, stream>>>(x, Wt, bq, bk, bv, Qimg, Kimg, VTimg);

  // chunk ladder on ws_size (constant per deployment -> same work every call)
  const size_t avail = ws_size > ((size_t)50 << 20) ? ws_size - ((size_t)50 << 20) : 0;
  int nchunk, nb, Ms;
  if      (avail >= ((size_t)128 << 20)) { nchunk = 1;  nb = 4; Ms = 4096; }
  else if (avail >= ((size_t)64  << 20)) { nchunk = 2;  nb = 2; Ms = 4096; }
  else if (avail >= ((size_t)32  << 20)) { nchunk = 4;  nb = 1; Ms = 4096; }
  else if (avail >= ((size_t)16  << 20)) { nchunk = 8;  nb = 1; Ms = 2048; }
  else if (avail >= ((size_t)8   << 20)) { nchunk = 16; nb = 1; Ms = 1024; }
  else                                   { nchunk = 32; nb = 1; Ms = 512;  }
  const int chunksPerBatch = 4096 / Ms;  // for nb==1 paths; nb>1 has Ms=4096

  for (int c = 0; c < nchunk; ++c) {
    int b0, s0;
    if (nb > 1 || Ms == 4096) { b0 = c * nb; s0 = 0; }
    else { b0 = c / chunksPerBatch; s0 = (c % chunksPerBatch) * Ms; }
    qk_kernel<<<dim3(32, Ms / 128, nb), dim3(256), 0, stream>>>(Qimg, Kimg, Simg, mEnc, b0, s0);
    pv_kernel<<<dim3(4, Ms / 64, nb), dim3(256), 0, stream>>>(Simg, VTimg, mEnc, out, b0, s0);
  }
}